// Round 1
// baseline (219.530 us; speedup 1.0000x reference)
//
#include <hip/hip_runtime.h>
#include <math.h>

// SE(3)-Transformer block, MI355X. B=4, N=192, CS=16, CV=4, DIM=28, NB=10.
// Strategy: per-node precompute of channel-contracted weight tensors T (kernel A),
// then per-(b,i) block with neighbor compaction (kernel B). All constants folded.

#define NN 192
#define TSTRIDE 2560   // floats per node in T: 2 fc * 16 h * 80

// Normalization constants (folded):
//  k_s = (fs@w1/4 + fvsh@w4/sqrt(12))/sqrt(2); k_v = (fs*sh1@w2/4 + fv@w3/2)/sqrt(2)
//  score = (qd_s.k_s/4 + qd_v.k_v/sqrt(12))/sqrt(2)
constexpr float C1   = 0.17677669529663687f;  // 1/(4*sqrt(2))  (w1 path)
constexpr float C2   = 0.17677669529663687f;  // 1/(4*sqrt(2))  (w2 path)
constexpr float C3   = 0.35355339059327373f;  // 1/(2*sqrt(2))  (w3 path)
constexpr float C4   = 0.20412414523193154f;  // 1/sqrt(24)     (w4 path)
constexpr float CS1f = 0.17677669529663687f;  // score scalar part
constexpr float CS2f = 0.20412414523193154f;  // score vector part
constexpr float RS10 = 0.31622776601683794f;  // 1/sqrt(10)
constexpr float GAIN4 = 1.679f * 0.25f;       // SILU_GAIN / sqrt(16)
constexpr float SQRT3 = 1.7320508075688772f;
constexpr float CEMB = (float)(1.14136 * 7.3890560989306495 * 3.1622776601683795); // 1.14136*e^2*sqrt(10)

// ---------------------------------------------------------------------------
// Kernel A: per-node precompute.
//  T layout per node: [fc(k=0,v=1)][h:16][chunk:80]
//   chunk: [0..15]  T1[o]   = C1 * sum_c fs[c]*W2[h, c*16+o]
//          [16..19] T2[o]   = C2 * sum_c fs[c]*W2[h, 256+c*4+o]
//          [20..31] T3[o*3+x] = C3 * sum_c fv[c][x]*W2[h, 320+c*4+o]
//          [32..79] T4[o*3+x] = C4 * sum_c fv[c][x]*W2[h, 336+c*16+o]
//  qd per node: [0..15] qd_s*CS1, [16..27] qd_v[d][x]*CS2
// ---------------------------------------------------------------------------
__global__ __launch_bounds__(128) void precomp(
  const float* __restrict__ f, const float* __restrict__ wq_s, const float* __restrict__ wq_v,
  const float* __restrict__ w2k, const float* __restrict__ w2v,
  const float* __restrict__ dws, const float* __restrict__ dwv,
  float* __restrict__ T, float* __restrict__ qd, float* __restrict__ validf)
{
  const int node = blockIdx.x;
  const int tid  = threadIdx.x;
  __shared__ float fsh[28];
  __shared__ float qs_sh[16], qv_sh[12];
  __shared__ int vsh;
  if (tid < 28) fsh[tid] = f[node*28 + tid];
  if (tid == 0) vsh = 0;
  __syncthreads();
  if (tid < 28) { if (fsh[tid] != 0.f) vsh = 1; }   // benign same-value race
  if (tid < 16) {
    float a = 0.f;
    #pragma unroll
    for (int c = 0; c < 16; ++c) a = fmaf(fsh[c], wq_s[c*16 + tid], a);
    qs_sh[tid] = a * 0.25f;
  } else if (tid < 28) {
    int idx = tid - 16, o = idx / 3, x = idx - o*3;
    float a = 0.f;
    #pragma unroll
    for (int c = 0; c < 4; ++c) a = fmaf(fsh[16 + c*3 + x], wq_v[c*4 + o], a);
    qv_sh[idx] = a * 0.5f;
  }
  __syncthreads();
  if (tid < 16) {
    float a = 0.f;
    #pragma unroll
    for (int c = 0; c < 16; ++c) a = fmaf(qs_sh[c], dws[c*16 + tid], a);
    qd[node*28 + tid] = a * CS1f;
  } else if (tid < 28) {
    int idx = tid - 16, d = idx / 3, x = idx - d*3;
    float a = 0.f;
    #pragma unroll
    for (int c = 0; c < 4; ++c) a = fmaf(qv_sh[c*3 + x], dwv[c*4 + d], a);
    qd[node*28 + tid] = a * CS2f;
  }
  if (tid == 0) validf[node] = vsh ? 1.f : 0.f;

  for (int e = tid; e < 2560; e += 128) {
    int fc = e / 1280, r = e - fc*1280, h = r / 80, q = r - h*80;
    const float* W = (fc ? w2v : w2k) + h*400;
    float val = 0.f;
    if (q < 16) {                       // T1: o=q, sum over 16 scalar channels
      #pragma unroll
      for (int c = 0; c < 16; ++c) val = fmaf(fsh[c], W[c*16 + q], val);
      val *= C1;
    } else if (q < 20) {                // T2: o=q-16
      int o = q - 16;
      #pragma unroll
      for (int c = 0; c < 16; ++c) val = fmaf(fsh[c], W[256 + c*4 + o], val);
      val *= C2;
    } else if (q < 32) {                // T3
      int p = q - 20, o = p / 3, x = p - o*3;
      #pragma unroll
      for (int c = 0; c < 4; ++c) val = fmaf(fsh[16 + c*3 + x], W[320 + c*4 + o], val);
      val *= C3;
    } else {                            // T4
      int p = q - 32, o = p / 3, x = p - o*3;
      #pragma unroll
      for (int c = 0; c < 4; ++c) val = fmaf(fsh[16 + c*3 + x], W[336 + c*16 + o], val);
      val *= C4;
    }
    T[(size_t)node*TSTRIDE + e] = val;
  }
}

// ---------------------------------------------------------------------------
// Kernel B: one block per (b,i). Compact active neighbors, compute score + v,
// normalize, reduce.
// ---------------------------------------------------------------------------
__global__ __launch_bounds__(192) void se3_main(
  const float* __restrict__ pos, const float* __restrict__ w1k, const float* __restrict__ w1v,
  const float* __restrict__ T, const float* __restrict__ qd, const float* __restrict__ validf,
  float* __restrict__ out)
{
  const int bi = blockIdx.x;
  const int b = bi / NN, i = bi - b*NN;
  const int tid = threadIdx.x;
  const int lane = tid & 63, wid = tid >> 6;

  __shared__ float qd_sh[28];
  __shared__ float w1k_sh[160], w1v_sh[160];
  __shared__ int   s_node[NN];
  __shared__ float s_dist[NN], s_cut[NN], s_shx[NN], s_shy[NN], s_shz[NN];
  __shared__ int   cnt_sh;
  __shared__ float zpart[3];
  __shared__ float opart[3][28];

  if (tid < 28) qd_sh[tid] = qd[bi*28 + tid];
  if (tid < 160) w1k_sh[tid] = w1k[tid] * RS10;       // fold 1/sqrt(10) into w1
  if (tid >= 32) w1v_sh[tid - 32] = w1v[tid - 32] * RS10;
  if (tid == 0) cnt_sh = 0;
  const float pix = pos[bi*3+0], piy = pos[bi*3+1], piz = pos[bi*3+2];
  const float vali = validf[bi];
  __syncthreads();

  // Phase 1: mask + compaction (one thread per j)
  {
    const int j = tid;
    const int nj = b*NN + j;
    const float dx = pos[nj*3+0]-pix, dy = pos[nj*3+1]-piy, dz = pos[nj*3+2]-piz;
    const float dist = sqrtf(fmaf(dx,dx,fmaf(dy,dy,dz*dz)) + 1e-12f);
    bool act = (j != i) && (dist < 1.5f) && (vali != 0.f) && (validf[nj] != 0.f);
    if (act) {
      const float cut = expf(-1.f / (10.f * (1.f - dist * (1.f/1.5f))));
      if (cut > 0.f) {
        const int s = atomicAdd(&cnt_sh, 1);
        const float sc = SQRT3 / dist;
        s_node[s] = nj; s_dist[s] = dist; s_cut[s] = cut;
        s_shx[s] = dx*sc; s_shy[s] = dy*sc; s_shz[s] = dz*sc;
      }
    }
  }
  __syncthreads();
  const int M = cnt_sh;

  float acc[28];     // v_s[0..15], v_v[16 + o*3 + x]
  #pragma unroll
  for (int c = 0; c < 28; ++c) acc[c] = 0.f;
  float le = 0.f;

  if (tid < M) {
    const int node = s_node[tid];
    const float dist = s_dist[tid], cut = s_cut[tid];
    const float shx = s_shx[tid], shy = s_shy[tid], shz = s_shz[tid];

    // radial basis (CEMB includes the *sqrt(10))
    float emb[10];
    #pragma unroll
    for (int k = 0; k < 10; ++k) {
      const float dd = (dist - (float)(k+1)*(1.5f/11.f)) * (11.f/1.5f);
      float e = 0.f;
      if (dd > -1.f && dd < 1.f) e = CEMB * expf(-1.f/(1.f+dd) - 1.f/(1.f-dd));
      emb[k] = e;
    }
    // FC hidden activations, scaled by GAIN/4 (w2 norm folded)
    float Hk[16], Hv[16];
    #pragma unroll
    for (int h = 0; h < 16; ++h) {
      float sk = 0.f, sv = 0.f;
      #pragma unroll
      for (int e = 0; e < 10; ++e) {
        sk = fmaf(emb[e], w1k_sh[e*16+h], sk);
        sv = fmaf(emb[e], w1v_sh[e*16+h], sv);
      }
      Hk[h] = GAIN4 * sk / (1.f + expf(-sk));
      Hv[h] = GAIN4 * sv / (1.f + expf(-sv));
    }

    const float4* __restrict__ Tk = (const float4*)(T + (size_t)node * TSTRIDE);

    // k-pass: accumulate k_s/k_v over h, then dot with qd -> score
    float ks[16], kv[12];
    #pragma unroll
    for (int o = 0; o < 16; ++o) ks[o] = 0.f;
    #pragma unroll
    for (int o = 0; o < 12; ++o) kv[o] = 0.f;
    #pragma unroll 1
    for (int h = 0; h < 16; ++h) {
      const float a = Hk[h];
      const float4* p = Tk + h*20;
      float cc[80];
      float4* cv4 = (float4*)cc;
      #pragma unroll
      for (int q = 0; q < 20; ++q) cv4[q] = p[q];
      #pragma unroll
      for (int o = 0; o < 16; ++o) {
        const float t4 = fmaf(cc[32+3*o], shx, fmaf(cc[33+3*o], shy, cc[34+3*o]*shz));
        ks[o] = fmaf(a, cc[o] + t4, ks[o]);
      }
      const float ax = a*shx, ay = a*shy, az = a*shz;
      #pragma unroll
      for (int o = 0; o < 4; ++o) {
        const float t2 = cc[16+o];
        kv[3*o+0] = fmaf(ax, t2, fmaf(a, cc[20+3*o+0], kv[3*o+0]));
        kv[3*o+1] = fmaf(ay, t2, fmaf(a, cc[20+3*o+1], kv[3*o+1]));
        kv[3*o+2] = fmaf(az, t2, fmaf(a, cc[20+3*o+2], kv[3*o+2]));
      }
    }
    float score = 0.f;
    #pragma unroll
    for (int o = 0; o < 16; ++o) score = fmaf(qd_sh[o], ks[o], score);
    #pragma unroll
    for (int o = 0; o < 12; ++o) score = fmaf(qd_sh[16+o], kv[o], score);
    le = cut * score;

    // v-pass
    const float4* __restrict__ Tv = Tk + 320;
    #pragma unroll 1
    for (int h = 0; h < 16; ++h) {
      const float a = Hv[h];
      const float4* p = Tv + h*20;
      float cc[80];
      float4* cv4 = (float4*)cc;
      #pragma unroll
      for (int q = 0; q < 20; ++q) cv4[q] = p[q];
      #pragma unroll
      for (int o = 0; o < 16; ++o) {
        const float t4 = fmaf(cc[32+3*o], shx, fmaf(cc[33+3*o], shy, cc[34+3*o]*shz));
        acc[o] = fmaf(a, cc[o] + t4, acc[o]);
      }
      const float ax = a*shx, ay = a*shy, az = a*shz;
      #pragma unroll
      for (int o = 0; o < 4; ++o) {
        const float t2 = cc[16+o];
        acc[16+3*o+0] = fmaf(ax, t2, fmaf(a, cc[20+3*o+0], acc[16+3*o+0]));
        acc[16+3*o+1] = fmaf(ay, t2, fmaf(a, cc[20+3*o+1], acc[16+3*o+1]));
        acc[16+3*o+2] = fmaf(az, t2, fmaf(a, cc[20+3*o+2], acc[16+3*o+2]));
      }
    }
  }

  // z reduction (sum of log_exp over the row)
  float z = le;
  #pragma unroll
  for (int d = 1; d < 64; d <<= 1) z += __shfl_xor(z, d);
  if (lane == 0) zpart[wid] = z;
  __syncthreads();
  z = zpart[0] + zpart[1] + zpart[2];
  if (z == 0.f) z = 1.f;
  const float alpha = le / z;
  const float att = alpha > 0.f ? sqrtf(alpha) : 0.f;

  // att-weighted output reduction across threads
  #pragma unroll
  for (int c = 0; c < 28; ++c) {
    float w = att * acc[c];
    #pragma unroll
    for (int d = 1; d < 64; d <<= 1) w += __shfl_xor(w, d);
    if (lane == 0) opart[wid][c] = w;
  }
  __syncthreads();
  if (tid < 28) out[bi*28 + tid] = opart[0][tid] + opart[1][tid] + opart[2][tid];
}

extern "C" void kernel_launch(void* const* d_in, const int* in_sizes, int n_in,
                              void* d_out, int out_size, void* d_ws, size_t ws_size,
                              hipStream_t stream) {
  const float* f      = (const float*)d_in[0];
  const float* pos    = (const float*)d_in[1];
  const float* wq_s   = (const float*)d_in[2];
  const float* wq_v   = (const float*)d_in[3];
  const float* fck_w1 = (const float*)d_in[4];
  const float* fck_w2 = (const float*)d_in[5];
  const float* fcv_w1 = (const float*)d_in[6];
  const float* fcv_w2 = (const float*)d_in[7];
  const float* dot_ws = (const float*)d_in[8];
  const float* dot_wv = (const float*)d_in[9];
  float* outp = (float*)d_out;

  const int BN = in_sizes[0] / 28;   // 768 nodes total (B*N)

  float* T  = (float*)d_ws;                       // BN * 2560
  float* qdp = T + (size_t)BN * TSTRIDE;          // BN * 28
  float* vf  = qdp + (size_t)BN * 28;             // BN

  precomp<<<BN, 128, 0, stream>>>(f, wq_s, wq_v, fck_w2, fcv_w2, dot_ws, dot_wv, T, qdp, vf);
  se3_main<<<BN, 192, 0, stream>>>(pos, fck_w1, fcv_w1, T, qdp, vf, outp);
}

// Round 7
// 102.773 us; speedup vs baseline: 2.1361x; 2.1361x over previous
//
#include <hip/hip_runtime.h>
#include <math.h>

// SE(3)-Transformer block, MI355X. B=4, N=192, CS=16, CV=4, DIM=28, NB=10.
// Round 5 candidate, resubmitted (round-6 bench failed on GPU acquisition).
// Fixes w1v LDS staging bug (w1_sh[256..319] unwritten with 256 threads ->
// garbage Hv -> absmax 114). Design: cooperative per-(pair,h) distribution +
// coalesced T layout [node][fc][q4:20][h:16] + LDS-staged W2 in precomp.

#define NN 192
#define TSTRIDE 2560   // floats per node in T: 2 fc * 20 q4 * 16 h * 4
#define MAXM 192

constexpr float C1   = 0.17677669529663687f;  // 1/(4*sqrt(2))  (w1 path)
constexpr float C2   = 0.17677669529663687f;  // 1/(4*sqrt(2))  (w2 path)
constexpr float C3   = 0.35355339059327373f;  // 1/(2*sqrt(2))  (w3 path)
constexpr float C4   = 0.20412414523193154f;  // 1/sqrt(24)     (w4 path)
constexpr float CS1f = 0.17677669529663687f;  // score scalar part
constexpr float CS2f = 0.20412414523193154f;  // score vector part
constexpr float RS10 = 0.31622776601683794f;  // 1/sqrt(10)
constexpr float GAIN4 = 1.679f * 0.25f;       // SILU_GAIN / sqrt(16)
constexpr float SQRT3 = 1.7320508075688772f;
constexpr float CEMB = (float)(1.14136 * 7.3890560989306495 * 3.1622776601683795); // 1.14136*e^2*sqrt(10)

// ---------------------------------------------------------------------------
// Kernel A: per-node precompute. W2 staged in LDS (51.2 KB), 256 threads.
//  T element (fc, h, chunk-float q80) stored at fc*1280 + (q80>>2)*64 + h*4 + (q80&3)
//  chunk semantics (per fc,h, 80 floats):
//   [0..15]  T1[o], [16..19] T2[o], [20..31] T3[o*3+x], [32..79] T4[o*3+x]
// ---------------------------------------------------------------------------
__global__ __launch_bounds__(256) void precomp(
  const float* __restrict__ f, const float* __restrict__ wq_s, const float* __restrict__ wq_v,
  const float* __restrict__ w2k, const float* __restrict__ w2v,
  const float* __restrict__ dws, const float* __restrict__ dwv,
  float* __restrict__ T, float* __restrict__ qd, float* __restrict__ validf)
{
  const int node = blockIdx.x;
  const int tid  = threadIdx.x;
  __shared__ float Wsh[12800];          // w2k (6400) then w2v (6400)
  __shared__ float fsh[28];
  __shared__ float qs_sh[16], qv_sh[12];
  __shared__ int vsh;
  if (tid == 0) vsh = 0;
  if (tid < 28) fsh[tid] = f[node*28 + tid];
  {
    float4* d = (float4*)Wsh;
    const float4* s0 = (const float4*)w2k;
    const float4* s1 = (const float4*)w2v;
    for (int q = tid; q < 1600; q += 256) { d[q] = s0[q]; d[1600 + q] = s1[q]; }
  }
  __syncthreads();
  if (tid < 28 && fsh[tid] != 0.f) vsh = 1;   // benign same-value race
  if (tid < 16) {
    float a = 0.f;
    #pragma unroll
    for (int c = 0; c < 16; ++c) a = fmaf(fsh[c], wq_s[c*16 + tid], a);
    qs_sh[tid] = a * 0.25f;
  } else if (tid < 28) {
    int idx = tid - 16, o = idx / 3, x = idx - o*3;
    float a = 0.f;
    #pragma unroll
    for (int c = 0; c < 4; ++c) a = fmaf(fsh[16 + c*3 + x], wq_v[c*4 + o], a);
    qv_sh[idx] = a * 0.5f;
  }
  __syncthreads();
  if (tid < 16) {
    float a = 0.f;
    #pragma unroll
    for (int c = 0; c < 16; ++c) a = fmaf(qs_sh[c], dws[c*16 + tid], a);
    qd[node*28 + tid] = a * CS1f;
  } else if (tid < 28) {
    int idx = tid - 16, d = idx / 3, x = idx - d*3;
    float a = 0.f;
    #pragma unroll
    for (int c = 0; c < 4; ++c) a = fmaf(qv_sh[c*3 + x], dwv[c*4 + d], a);
    qd[node*28 + tid] = a * CS2f;
  }
  if (tid == 0) validf[node] = vsh ? 1.f : 0.f;

  for (int e = tid; e < 2560; e += 256) {
    const int fc = e >= 1280 ? 1 : 0;
    const int r = e - fc*1280;
    const int h = r / 80, q = r - h*80;
    const float* W = Wsh + fc*6400 + h*400;
    float val = 0.f;
    if (q < 16) {                       // T1
      #pragma unroll
      for (int c = 0; c < 16; ++c) val = fmaf(fsh[c], W[c*16 + q], val);
      val *= C1;
    } else if (q < 20) {                // T2
      const int o = q - 16;
      #pragma unroll
      for (int c = 0; c < 16; ++c) val = fmaf(fsh[c], W[256 + c*4 + o], val);
      val *= C2;
    } else if (q < 32) {                // T3
      const int p = q - 20, o = p / 3, x = p - o*3;
      #pragma unroll
      for (int c = 0; c < 4; ++c) val = fmaf(fsh[16 + c*3 + x], W[320 + c*4 + o], val);
      val *= C3;
    } else {                            // T4
      const int p = q - 32, o = p / 3, x = p - o*3;
      #pragma unroll
      for (int c = 0; c < 4; ++c) val = fmaf(fsh[16 + c*3 + x], W[336 + c*16 + o], val);
      val *= C4;
    }
    T[(size_t)node*TSTRIDE + fc*1280 + (q >> 2)*64 + h*4 + (q & 3)] = val;
  }
}

// ---------------------------------------------------------------------------
// Kernel B: one block (256 thr) per (b,i). Compaction, then (pair,h) items
// spread over all threads. 16-lane groups share a pair -> coalesced 256B loads.
// ---------------------------------------------------------------------------
__global__ __launch_bounds__(256) void se3_main(
  const float* __restrict__ pos, const float* __restrict__ w1k, const float* __restrict__ w1v,
  const float* __restrict__ T, const float* __restrict__ qd, const float* __restrict__ validf,
  float* __restrict__ out)
{
  const int bi = blockIdx.x;
  const int b = bi / NN, i = bi - b*NN;
  const int tid = threadIdx.x;
  const int lane = tid & 63, wid = tid >> 6;

  __shared__ float qd_sh[28];
  __shared__ float w1_sh[320];                 // k(160) then v(160), pre-scaled
  __shared__ int   s_node[MAXM];
  __shared__ float s_cut[MAXM], s_dist[MAXM];
  __shared__ float s_shx[MAXM], s_shy[MAXM], s_shz[MAXM];
  __shared__ float emb_sh[MAXM*10];
  __shared__ float Hk_sh[MAXM*16];
  __shared__ float Hv_sh[MAXM*16];
  __shared__ float le_sh[MAXM];
  __shared__ float att_sh[MAXM];
  __shared__ int   cnt_sh;
  __shared__ float red_sh[4];
  __shared__ float opart[4][28];

  if (tid < 28) qd_sh[tid] = qd[bi*28 + tid];
  if (tid < 160) {                              // covers all 320 entries
    w1_sh[tid]       = w1k[tid] * RS10;
    w1_sh[160 + tid] = w1v[tid] * RS10;
  }
  if (tid == 0) cnt_sh = 0;
  const float pix = pos[bi*3+0], piy = pos[bi*3+1], piz = pos[bi*3+2];
  const float vali = validf[bi];
  __syncthreads();

  // Phase 1: mask + compaction
  if (tid < NN) {
    const int nj = b*NN + tid;
    const float dx = pos[nj*3+0]-pix, dy = pos[nj*3+1]-piy, dz = pos[nj*3+2]-piz;
    const float dist = sqrtf(fmaf(dx,dx,fmaf(dy,dy,dz*dz)) + 1e-12f);
    if (tid != i && dist < 1.5f && vali != 0.f && validf[nj] != 0.f) {
      const float cut = expf(-1.f / (10.f * (1.f - dist * (1.f/1.5f))));
      if (cut > 0.f) {
        const int s = atomicAdd(&cnt_sh, 1);
        const float sc = SQRT3 / dist;
        s_node[s] = nj; s_cut[s] = cut; s_dist[s] = dist;
        s_shx[s] = dx*sc; s_shy[s] = dy*sc; s_shz[s] = dz*sc;
      }
    }
  }
  __syncthreads();
  const int M = cnt_sh;
  const int MK = M * 16;

  // Phase 2a: radial basis per (pair, k)
  for (int idx = tid; idx < M*10; idx += 256) {
    const int pr = idx / 10, k = idx - pr*10;
    const float dd = (s_dist[pr] - (float)(k+1)*(1.5f/11.f)) * (11.f/1.5f);
    float e = 0.f;
    if (dd > -1.f && dd < 1.f) e = CEMB * expf(-1.f/(1.f+dd) - 1.f/(1.f-dd));
    emb_sh[idx] = e;
  }
  __syncthreads();

  // Phase 2b: FC hidden per (pair, fc, h)
  for (int idx = tid; idx < M*32; idx += 256) {
    const int pr = idx >> 5, t = idx & 31, h = t & 15;
    const float* w = w1_sh + (t >> 4)*160;
    const float* e = emb_sh + pr*10;
    float s = 0.f;
    #pragma unroll
    for (int q = 0; q < 10; ++q) s = fmaf(e[q], w[q*16 + h], s);
    const float hh = GAIN4 * s / (1.f + expf(-s));
    float* dst = (t < 16) ? Hk_sh : Hv_sh;
    dst[pr*16 + h] = hh;
  }
  __syncthreads();

  // Phase 2c: k-pass -> per-pair raw score in le_sh
  for (int idx = tid; idx < MK; idx += 256) {
    const int pr = idx >> 4, h = idx & 15;
    const int node = s_node[pr];
    const float sx = s_shx[pr], sy = s_shy[pr], sz = s_shz[pr];
    const float a = Hk_sh[idx];
    const float4* b4 = (const float4*)(T + (size_t)node*TSTRIDE);
    float cc[80];
    float4* c4 = (float4*)cc;
    #pragma unroll
    for (int q = 0; q < 20; ++q) c4[q] = b4[q*16 + h];
    float s = 0.f;
    #pragma unroll
    for (int o = 0; o < 16; ++o) {
      const float t4 = fmaf(cc[32+3*o], sx, fmaf(cc[33+3*o], sy, cc[34+3*o]*sz));
      s = fmaf(qd_sh[o], cc[o] + t4, s);
    }
    #pragma unroll
    for (int o = 0; o < 4; ++o) {
      const float qvs = fmaf(qd_sh[16+3*o], sx, fmaf(qd_sh[17+3*o], sy, qd_sh[18+3*o]*sz));
      s = fmaf(qvs, cc[16+o], s);
      s = fmaf(qd_sh[16+3*o], cc[20+3*o+0], s);
      s = fmaf(qd_sh[17+3*o], cc[20+3*o+1], s);
      s = fmaf(qd_sh[18+3*o], cc[20+3*o+2], s);
    }
    s *= a;
    #pragma unroll
    for (int d = 1; d < 16; d <<= 1) s += __shfl_xor(s, d);   // MK multiple of 16 -> uniform per 16-group
    if ((tid & 15) == 0) le_sh[pr] = s;
  }
  __syncthreads();

  // z + att per pair
  float les = 0.f;
  if (tid < M) les = s_cut[tid] * le_sh[tid];
  float z = les;
  #pragma unroll
  for (int d = 1; d < 64; d <<= 1) z += __shfl_xor(z, d);
  if (lane == 0) red_sh[wid] = z;
  __syncthreads();
  z = red_sh[0] + red_sh[1] + red_sh[2] + red_sh[3];
  if (z == 0.f) z = 1.f;
  if (tid < M) {
    const float alpha = les / z;
    att_sh[tid] = alpha > 0.f ? sqrtf(alpha) : 0.f;
  }
  __syncthreads();

  // Phase 3: v-pass with att folded in
  float acc[28];
  #pragma unroll
  for (int c = 0; c < 28; ++c) acc[c] = 0.f;
  for (int idx = tid; idx < MK; idx += 256) {
    const int pr = idx >> 4, h = idx & 15;
    const int node = s_node[pr];
    const float sx = s_shx[pr], sy = s_shy[pr], sz = s_shz[pr];
    const float a = Hv_sh[idx] * att_sh[pr];
    const float4* b4 = (const float4*)(T + (size_t)node*TSTRIDE + 1280);
    float cc[80];
    float4* c4 = (float4*)cc;
    #pragma unroll
    for (int q = 0; q < 20; ++q) c4[q] = b4[q*16 + h];
    #pragma unroll
    for (int o = 0; o < 16; ++o) {
      const float t4 = fmaf(cc[32+3*o], sx, fmaf(cc[33+3*o], sy, cc[34+3*o]*sz));
      acc[o] = fmaf(a, cc[o] + t4, acc[o]);
    }
    const float ax = a*sx, ay = a*sy, az = a*sz;
    #pragma unroll
    for (int o = 0; o < 4; ++o) {
      const float t2 = cc[16+o];
      acc[16+3*o+0] = fmaf(ax, t2, fmaf(a, cc[20+3*o+0], acc[16+3*o+0]));
      acc[16+3*o+1] = fmaf(ay, t2, fmaf(a, cc[20+3*o+1], acc[16+3*o+1]));
      acc[16+3*o+2] = fmaf(az, t2, fmaf(a, cc[20+3*o+2], acc[16+3*o+2]));
    }
  }

  // block-wide 28-element reduction
  #pragma unroll
  for (int c = 0; c < 28; ++c) {
    float w = acc[c];
    #pragma unroll
    for (int d = 1; d < 64; d <<= 1) w += __shfl_xor(w, d);
    if (lane == 0) opart[wid][c] = w;
  }
  __syncthreads();
  if (tid < 28) out[bi*28 + tid] = opart[0][tid] + opart[1][tid] + opart[2][tid] + opart[3][tid];
}

extern "C" void kernel_launch(void* const* d_in, const int* in_sizes, int n_in,
                              void* d_out, int out_size, void* d_ws, size_t ws_size,
                              hipStream_t stream) {
  const float* f      = (const float*)d_in[0];
  const float* pos    = (const float*)d_in[1];
  const float* wq_s   = (const float*)d_in[2];
  const float* wq_v   = (const float*)d_in[3];
  const float* fck_w1 = (const float*)d_in[4];
  const float* fck_w2 = (const float*)d_in[5];
  const float* fcv_w1 = (const float*)d_in[6];
  const float* fcv_w2 = (const float*)d_in[7];
  const float* dot_ws = (const float*)d_in[8];
  const float* dot_wv = (const float*)d_in[9];
  float* outp = (float*)d_out;

  const int BN = in_sizes[0] / 28;   // 768 nodes total (B*N)

  float* T   = (float*)d_ws;                      // BN * 2560
  float* qdp = T + (size_t)BN * TSTRIDE;          // BN * 28
  float* vf  = qdp + (size_t)BN * 28;             // BN

  precomp<<<BN, 256, 0, stream>>>(f, wq_s, wq_v, fck_w2, fcv_w2, dot_ws, dot_wv, T, qdp, vf);
  se3_main<<<BN, 256, 0, stream>>>(pos, fck_w1, fcv_w1, T, qdp, vf, outp);
}